// Round 7
// baseline (124.490 us; speedup 1.0000x reference)
//
#include <hip/hip_runtime.h>
#include <math.h>

// LorentzConv1d bf16-MFMA, round 7: round-6 structure with the DPP reduction
// corrected. row_shr:1/2/4/8 accumulates toward the TOP lane of each 16-lane
// DPP row (AMD cross-lane reference), so the row total is valid in col 15.
// Col 15 of each half publishes the sum to LDS; after the barrier col 0 reads
// both halves and forms the Lorentz time output.

#define BSZ   16
#define LLEN  8192
#define CIN   64
#define COUT  64
#define KW    5
#define LINF  316
#define MTILE 64
#define ROWS  68            // MTILE + 2*PAD
#define ASTR  72            // LDS row stride (bf16): 144 B, 16B-aligned
#define TPB   4             // tiles per block
#define NTILES (BSZ * LLEN / MTILE)   // 2048
#define GRID   (NTILES / TPB)         // 512

typedef __attribute__((ext_vector_type(8))) short  short8;
typedef __attribute__((ext_vector_type(4))) float  float4v;

__device__ inline unsigned short f2bf(float f) {
    unsigned u = __builtin_bit_cast(unsigned int, f);
    u += 0x7FFFu + ((u >> 16) & 1u);
    return (unsigned short)(u >> 16);
}

template <int CTRL>
__device__ inline float dpp_add(float v) {
    int x = __builtin_bit_cast(int, v);
    int t = __builtin_amdgcn_update_dpp(0, x, CTRL, 0xF, 0xF, true);
    return v + __builtin_bit_cast(float, t);
}

// sum over each 16-lane DPP row (= MFMA col group); result valid in col 15.
__device__ inline float dpp_rowsum16_hi(float v) {
    v = dpp_add<0x111>(v);   // row_shr:1  (lane i += lane i-1)
    v = dpp_add<0x112>(v);   // row_shr:2
    v = dpp_add<0x114>(v);   // row_shr:4
    v = dpp_add<0x118>(v);   // row_shr:8  -> lane 15 of each row = row total
    return v;
}

__global__ __launch_bounds__(256) void lorentz_mfma(
    const float* __restrict__ x, const float* __restrict__ W,
    const float* __restrict__ bias, float* __restrict__ out)
{
    __shared__ unsigned short At[2][ROWS * ASTR];
    __shared__ float tcol[2][72];
    __shared__ float pss[2][2][64];        // [buf][nhalf][row]

    int tid  = threadIdx.x;
    int lane = tid & 63;
    int wv   = tid >> 6;
    int col  = lane & 15, quad = lane >> 4;
    int nhalf = wv & 1;                    // which 32 of 64 output cols
    int mbase = (wv >> 1) * 32;            // which 32 of 64 rows

    int tile0 = blockIdx.x * TPB;

    float4 sreg[5];
    bool   sin[5];

    auto stage_load = [&](int tile) {
        int b  = tile >> 7;                // 128 tiles per batch row
        int l0 = (tile & 127) * MTILE;
        const float* xb = x + ((size_t)b * LLEN) * CIN;
        #pragma unroll
        for (int itc = 0; itc < 5; ++itc) {
            int i = tid + itc * 256;
            if (i < ROWS * 16) {
                int r = i >> 4, ch = i & 15;
                int row = l0 - 2 + r;
                sin[itc] = (row >= 0) && (row < LLEN);
                int rowc = min(max(row, 0), LLEN - 1);
                sreg[itc] = ((const float4*)(xb + (size_t)rowc * CIN))[ch];
            }
        }
    };
    auto stage_write = [&](int nb) {
        #pragma unroll
        for (int itc = 0; itc < 5; ++itc) {
            int i = tid + itc * 256;
            if (i < ROWS * 16) {
                int r = i >> 4, ch = i & 15;
                float4 v = sreg[itc];
                if (!sin[itc]) { v.x = (ch == 0) ? 1.f : 0.f; v.y = 0.f; v.z = 0.f; v.w = 0.f; }
                if (ch == 0) tcol[nb][r] = v.x;
                ushort4 pk;
                pk.x = f2bf(v.x); pk.y = f2bf(v.y); pk.z = f2bf(v.z); pk.w = f2bf(v.w);
                *(ushort4*)&At[nb][r * ASTR + ch * 4] = pk;
            }
        }
    };

    // ---- prologue: issue tile-0 staging loads first ----
    stage_load(tile0);

    // ---- build B panel in registers from W (one-time, L2-hot gather) ----
    // frag kk = tap*2+ks, element e -> channel c = ks*32 + quad*8 + e;
    // weight = W[n][1+(c-1)*5+tap], c==0 -> 0.
    short8 breg[2][10];
    float bo[2], w0[2];
    #pragma unroll
    for (int j = 0; j < 2; ++j) {
        int n = nhalf * 32 + j * 16 + col;
        const float* wrow = W + (size_t)n * LINF;
        #pragma unroll
        for (int kk = 0; kk < 10; ++kk) {
            int tap = kk >> 1, ks = kk & 1;
            short8 t;
            #pragma unroll
            for (int e = 0; e < 8; ++e) {
                int c = ks * 32 + quad * 8 + e;
                float v = (c == 0) ? 0.f : wrow[1 + (c - 1) * KW + tap];
                t[e] = (short)f2bf(v);
            }
            breg[j][kk] = t;
        }
        bo[j] = bias[n];
        w0[j] = wrow[0];                   // time-feature weight
    }

    stage_write(0);
    __syncthreads();

    int cur = 0;
    #pragma unroll
    for (int it = 0; it < TPB; ++it) {
        int tile = tile0 + it;
        bool more = (it + 1 < TPB);
        if (more) stage_load(tile + 1);    // next tile's loads in flight

        // ---- K-loop: pure LDS + MFMA ----
        float4v acc[2][2];                 // [msub][j]
        #pragma unroll
        for (int ms = 0; ms < 2; ++ms)
            #pragma unroll
            for (int j = 0; j < 2; ++j)
                acc[ms][j] = (float4v){0.f, 0.f, 0.f, 0.f};
        #pragma unroll
        for (int kk = 0; kk < 10; ++kk) {
            int tap = kk >> 1, ks = kk & 1;
            #pragma unroll
            for (int ms = 0; ms < 2; ++ms) {
                short8 afr = *(const short8*)&At[cur][(mbase + ms * 16 + col + tap) * ASTR
                                                     + ks * 32 + quad * 8];
                acc[ms][0] = __builtin_amdgcn_mfma_f32_16x16x32_bf16(afr, breg[0][kk], acc[ms][0], 0, 0, 0);
                acc[ms][1] = __builtin_amdgcn_mfma_f32_16x16x32_bf16(afr, breg[1][kk], acc[ms][1], 0, 0, 0);
            }
        }

        // ---- t_resc per (msub, reg) from fp32 time column ----
        float trs[2][4];
        #pragma unroll
        for (int ms = 0; ms < 2; ++ms) {
            int p0 = mbase + ms * 16 + quad * 4;
            float4 a = *(const float4*)&tcol[cur][p0];
            float4 c = *(const float4*)&tcol[cur][p0 + 4];
            float tw[8] = {a.x, a.y, a.z, a.w, c.x, c.y, c.z, c.w};
            #pragma unroll
            for (int reg = 0; reg < 4; ++reg) {
                float s = 0.f;
                #pragma unroll
                for (int t = 0; t < KW; ++t) { float v = tw[reg + t]; s += v * v; }
                trs[ms][reg] = sqrtf(s - (float)(KW - 1));
            }
        }

        // ---- partial epilogue: y, per-row ssq over this wave's 32 cols ----
        float y[2][2][4];                  // [ms][j][reg]
        float sq[2][4];
        #pragma unroll
        for (int ms = 0; ms < 2; ++ms)
            #pragma unroll
            for (int reg = 0; reg < 4; ++reg) {
                float s = 0.f;
                #pragma unroll
                for (int j = 0; j < 2; ++j) {
                    float v = acc[ms][j][reg] + bo[j] + trs[ms][reg] * w0[j];
                    y[ms][j][reg] = v;
                    bool isc0 = (nhalf == 0) && (j == 0) && (col == 0);
                    s += isc0 ? 0.f : v * v;
                }
                sq[ms][reg] = s;
            }
        #pragma unroll
        for (int ms = 0; ms < 2; ++ms)
            #pragma unroll
            for (int reg = 0; reg < 4; ++reg) {
                float rs = dpp_rowsum16_hi(sq[ms][reg]);   // valid in col 15
                if (col == 15)
                    pss[cur][nhalf][mbase + ms * 16 + quad * 4 + reg] = rs;
            }

        if (more) stage_write(cur ^ 1);    // convert + fill other buffer
        __syncthreads();                   // publishes pss[cur] AND At[cur^1]

        // ---- finish: combine halves, Lorentz-replace o=0, store ----
        #pragma unroll
        for (int ms = 0; ms < 2; ++ms)
            #pragma unroll
            for (int reg = 0; reg < 4; ++reg) {
                int row = mbase + ms * 16 + quad * 4 + reg;
                if (nhalf == 0 && col == 0) {
                    float tot = pss[cur][0][row] + pss[cur][1][row];
                    y[ms][0][reg] = sqrtf(tot + 1.f);
                }
                float* orow = out + ((size_t)tile * MTILE + row) * COUT + nhalf * 32 + col;
                orow[0]  = y[ms][0][reg];
                orow[16] = y[ms][1][reg];
            }
        cur ^= 1;
    }
}

extern "C" void kernel_launch(void* const* d_in, const int* in_sizes, int n_in,
                              void* d_out, int out_size, void* d_ws, size_t ws_size,
                              hipStream_t stream) {
    const float* x    = (const float*)d_in[0];
    const float* W    = (const float*)d_in[1];
    const float* bias = (const float*)d_in[2];
    float* out = (float*)d_out;

    hipLaunchKernelGGL(lorentz_mfma, dim3(GRID), dim3(256), 0, stream,
                       x, W, bias, out);
}

// Round 8
// 98.027 us; speedup vs baseline: 1.2700x; 1.2700x over previous
//
#include <hip/hip_runtime.h>
#include <math.h>

// LorentzConv1d bf16-MFMA, round 8: revert the W-gather regression (two-kernel
// structure: prep_W -> compact Wb, 64B-aligned rows), 16 output cols per wave
// (breg 40 VGPR) so the kernel fits 128 VGPR -> launch_bounds(256,4), 4 blocks
// /CU resident. TPB=2, grid=1024, double-buffered LDS staging, col-15 DPP
// epilogue with 4-way cross-wave ssq combine via LDS.

#define BSZ   16
#define LLEN  8192
#define CIN   64
#define COUT  64
#define KW    5
#define LINF  316
#define MTILE 64
#define ROWS  68            // MTILE + 2*PAD
#define ASTR  72            // LDS row stride (bf16): 144 B, 16B-aligned
#define KB    320           // 5 taps * 64 channels
#define TPB   2
#define NTILES (BSZ * LLEN / MTILE)   // 2048
#define GRID   (NTILES / TPB)         // 1024

typedef __attribute__((ext_vector_type(8))) short  short8;
typedef __attribute__((ext_vector_type(4))) float  float4v;

__device__ inline unsigned short f2bf(float f) {
    unsigned u = __builtin_bit_cast(unsigned int, f);
    u += 0x7FFFu + ((u >> 16) & 1u);
    return (unsigned short)(u >> 16);
}

template <int CTRL>
__device__ inline float dpp_add(float v) {
    int x = __builtin_bit_cast(int, v);
    int t = __builtin_amdgcn_update_dpp(0, x, CTRL, 0xF, 0xF, true);
    return v + __builtin_bit_cast(float, t);
}

// sum over each 16-lane DPP row; result valid in lane 15 of the row (verified R7).
__device__ inline float dpp_rowsum16_hi(float v) {
    v = dpp_add<0x111>(v);
    v = dpp_add<0x112>(v);
    v = dpp_add<0x114>(v);
    v = dpp_add<0x118>(v);
    return v;
}

// Wb[n*320 + tap*64 + c] = bf16(W[n][1+(c-1)*5+tap]), c==0 slot = 0.
__global__ __launch_bounds__(256) void prep_W(const float* __restrict__ W,
                                              unsigned short* __restrict__ Wb) {
    int i = blockIdx.x * 256 + threadIdx.x;
    if (i >= COUT * KB) return;
    int n   = i / KB;
    int kk  = i - n * KB;
    int tap = kk >> 6;
    int c   = kk & 63;
    float v = (c == 0) ? 0.f : W[n * LINF + 1 + (c - 1) * KW + tap];
    Wb[i] = f2bf(v);
}

__global__ __launch_bounds__(256, 4) void lorentz_mfma(
    const float* __restrict__ x, const unsigned short* __restrict__ Wb,
    const float* __restrict__ W, const float* __restrict__ bias,
    float* __restrict__ out)
{
    __shared__ unsigned short At[2][ROWS * ASTR];
    __shared__ float tcol[2][72];
    __shared__ float pss[2][4][64];        // [buf][wave(nq)][row]

    int tid  = threadIdx.x;
    int lane = tid & 63;
    int nq   = tid >> 6;                   // wave = N-quarter (16 cols)
    int col  = lane & 15, quad = lane >> 4;
    int n    = nq * 16 + col;              // this lane's output channel

    int tile0 = blockIdx.x * TPB;

    float4 sreg[5];
    bool   sin[5];

    auto stage_load = [&](int tile) {
        int b  = tile >> 7;                // 128 tiles per batch row
        int l0 = (tile & 127) * MTILE;
        const float* xb = x + ((size_t)b * LLEN) * CIN;
        #pragma unroll
        for (int itc = 0; itc < 5; ++itc) {
            int i = tid + itc * 256;
            if (i < ROWS * 16) {
                int r = i >> 4, ch = i & 15;
                int row = l0 - 2 + r;
                sin[itc] = (row >= 0) && (row < LLEN);
                int rowc = min(max(row, 0), LLEN - 1);
                sreg[itc] = ((const float4*)(xb + (size_t)rowc * CIN))[ch];
            }
        }
    };
    auto stage_write = [&](int nb) {
        #pragma unroll
        for (int itc = 0; itc < 5; ++itc) {
            int i = tid + itc * 256;
            if (i < ROWS * 16) {
                int r = i >> 4, ch = i & 15;
                float4 v = sreg[itc];
                if (!sin[itc]) { v.x = (ch == 0) ? 1.f : 0.f; v.y = 0.f; v.z = 0.f; v.w = 0.f; }
                if (ch == 0) tcol[nb][r] = v.x;
                ushort4 pk;
                pk.x = f2bf(v.x); pk.y = f2bf(v.y); pk.z = f2bf(v.z); pk.w = f2bf(v.w);
                *(ushort4*)&At[nb][r * ASTR + ch * 4] = pk;
            }
        }
    };

    // ---- prologue ----
    stage_load(tile0);

    // B panel: 10 frags from compact Wb (rows 640 B, 64B-aligned -> cheap gather)
    short8 breg[10];
    {
        const unsigned short* bp = Wb + (size_t)n * KB + quad * 8;
        #pragma unroll
        for (int kk = 0; kk < 10; ++kk)
            breg[kk] = *(const short8*)(bp + kk * 32);
    }
    float bo = bias[n];
    float w0 = W[(size_t)n * LINF];        // time-feature weight

    stage_write(0);
    __syncthreads();

    int cur = 0;
    #pragma unroll
    for (int it = 0; it < TPB; ++it) {
        int tile = tile0 + it;
        bool more = (it + 1 < TPB);
        if (more) stage_load(tile + 1);

        // ---- K-loop: pure LDS + MFMA (4 M-subtiles x 10 ksteps) ----
        float4v acc[4];
        #pragma unroll
        for (int ms = 0; ms < 4; ++ms) acc[ms] = (float4v){0.f, 0.f, 0.f, 0.f};
        #pragma unroll
        for (int kk = 0; kk < 10; ++kk) {
            int tap = kk >> 1, ks = kk & 1;
            #pragma unroll
            for (int ms = 0; ms < 4; ++ms) {
                short8 afr = *(const short8*)&At[cur][(ms * 16 + col + tap) * ASTR
                                                     + ks * 32 + quad * 8];
                acc[ms] = __builtin_amdgcn_mfma_f32_16x16x32_bf16(afr, breg[kk], acc[ms], 0, 0, 0);
            }
        }

        // ---- fold bias + t_resc*w0 into acc; per-row ssq partial + DPP ----
        #pragma unroll
        for (int ms = 0; ms < 4; ++ms) {
            int p0 = ms * 16 + quad * 4;
            float4 a = *(const float4*)&tcol[cur][p0];
            float4 c = *(const float4*)&tcol[cur][p0 + 4];
            float tw[8] = {a.x, a.y, a.z, a.w, c.x, c.y, c.z, c.w};
            float sq[4];
            #pragma unroll
            for (int reg = 0; reg < 4; ++reg) {
                float s = 0.f;
                #pragma unroll
                for (int t = 0; t < KW; ++t) { float v = tw[reg + t]; s += v * v; }
                float trs = sqrtf(s - (float)(KW - 1));
                float v = acc[ms][reg] + bo + trs * w0;
                acc[ms][reg] = v;
                bool isc0 = (nq == 0) && (col == 0);   // o = 0 excluded
                sq[reg] = isc0 ? 0.f : v * v;
            }
            #pragma unroll
            for (int reg = 0; reg < 4; ++reg) {
                float rs = dpp_rowsum16_hi(sq[reg]);   // valid in col 15
                if (col == 15)
                    pss[cur][nq][ms * 16 + quad * 4 + reg] = rs;
            }
        }

        if (more) stage_write(cur ^ 1);
        __syncthreads();                   // publishes pss[cur] AND At[cur^1]

        // ---- store: Lorentz-replace o=0, 16 cols per wave ----
        #pragma unroll
        for (int ms = 0; ms < 4; ++ms) {
            #pragma unroll
            for (int reg = 0; reg < 4; ++reg) {
                int row = ms * 16 + quad * 4 + reg;
                float v = acc[ms][reg];
                if (nq == 0 && col == 0) {
                    float tot = pss[cur][0][row] + pss[cur][1][row]
                              + pss[cur][2][row] + pss[cur][3][row];
                    v = sqrtf(tot + 1.f);
                }
                out[((size_t)tile * MTILE + row) * COUT + n] = v;
            }
        }
        cur ^= 1;
    }
}

extern "C" void kernel_launch(void* const* d_in, const int* in_sizes, int n_in,
                              void* d_out, int out_size, void* d_ws, size_t ws_size,
                              hipStream_t stream) {
    const float* x    = (const float*)d_in[0];
    const float* W    = (const float*)d_in[1];
    const float* bias = (const float*)d_in[2];
    float* out = (float*)d_out;
    unsigned short* Wb = (unsigned short*)d_ws;   // 40960 B scratch

    hipLaunchKernelGGL(prep_W, dim3((COUT * KB + 255) / 256), dim3(256), 0, stream,
                       W, Wb);
    hipLaunchKernelGGL(lorentz_mfma, dim3(GRID), dim3(256), 0, stream,
                       x, Wb, W, bias, out);
}